// Round 1
// baseline (362.159 us; speedup 1.0000x reference)
//
#include <hip/hip_runtime.h>
#include <math.h>

#define M_ 64
#define N_ 2048
#define D_ 256
#define L_ 64
#define J_ 384
#define CHUNKS 16
#define CN 128   // N_/CHUNKS

// ---- ws byte offsets ----
#define OFF_Q     0u          // [J_][64] f32 : 98304 B
#define OFF_LG    98304u      // [J_] f32     : 1536 B
#define OFF_SQX   99840u      // [M_] f32
#define OFF_SQT   100096u     // [N_] f32
#define OFF_PRED  108288u     // [M_*2] f32
#define OFF_CHUNK 108800u     // [M_][CHUNKS][64] double : 524288 B
#define OFF_OFFS  633088u     // [M_][CHUNKS][64] double
#define OFF_TOT   1157376u    // [M_][64] double
#define OFF_PSUM  1190144u    // [M_*N_][64] f32 : 33554432 B

__global__ __launch_bounds__(512)
void k_setup(const float* __restrict__ buckets, char* __restrict__ ws) {
    float* Q    = (float*)(ws + OFF_Q);
    float* lg   = (float*)(ws + OFF_LG);
    float* pred = (float*)(ws + OFF_PRED);
    int t = threadIdx.x;
    if (t < 64) {
        // x_l = 0.5 * buckets[l] / SIGMA2 = buckets[l]/8
        double x = (double)buckets[t] * 0.125;
        const double a0 = 128.0;   // 0.5*D
        double gln = lgamma(a0);
        double q;
        if (x < a0 + 1.0) {
            // series for P(a0,x), then Q = 1-P (P small or moderate here)
            double ap = a0, sum = 1.0 / a0, del = sum;
            for (int it = 0; it < 4000; ++it) {
                ap += 1.0; del *= x / ap; sum += del;
                if (fabs(del) < fabs(sum) * 1e-17) break;
            }
            q = 1.0 - sum * exp(-x + a0 * log(x) - gln);
        } else {
            // Lentz continued fraction for Q(a0,x) (relative-accurate for small Q)
            double b = x + 1.0 - a0, c = 1e300, d = 1.0 / b, h = d;
            for (int i = 1; i <= 4000; ++i) {
                double an = -(double)i * ((double)i - a0);
                b += 2.0;
                d = an * d + b; if (fabs(d) < 1e-300) d = 1e-300;
                c = b + an / c; if (fabs(c) < 1e-300) c = 1e-300;
                d = 1.0 / d;
                double delc = d * c; h *= delc;
                if (fabs(delc - 1.0) < 1e-16) break;
            }
            q = exp(-x + a0 * log(x) - gln) * h;
        }
        // t_a = x^a e^-x / Gamma(a+1) at a=a0 ; Q(a+1,x)=Q(a,x)+t_a
        double tt = exp(a0 * log(x) - x - lgamma(a0 + 1.0));
        for (int j = 0; j < J_; ++j) {
            Q[j * 64 + t] = (float)q;
            q += tt; if (q > 1.0) q = 1.0;
            tt *= x / (a0 + (double)j + 1.0);
        }
    } else if (t < 64 + J_) {
        int j = t - 64;
        lg[j] = (float)lgamma((double)(j + 1));
    } else if (t < 64 + J_ + 64) {
        int i = t - (64 + J_);
        pred[2 * i] = 0.f; pred[2 * i + 1] = 0.f;
    }
}

__global__ __launch_bounds__(256)
void k_sq(const float* __restrict__ X, const float* __restrict__ TX, char* __restrict__ ws) {
    float* sqX = (float*)(ws + OFF_SQX);
    float* sqT = (float*)(ws + OFF_SQT);
    int t = blockIdx.x * 256 + threadIdx.x;
    if (t < M_) {
        const float4* r = (const float4*)(X + t * D_);
        float s0 = 0, s1 = 0, s2 = 0, s3 = 0;
        for (int i = 0; i < D_ / 4; ++i) {
            float4 v = r[i];
            s0 = fmaf(v.x, v.x, s0); s1 = fmaf(v.y, v.y, s1);
            s2 = fmaf(v.z, v.z, s2); s3 = fmaf(v.w, v.w, s3);
        }
        sqX[t] = (s0 + s1) + (s2 + s3);
    } else if (t < M_ + N_) {
        int n = t - M_;
        const float4* r = (const float4*)(TX + n * D_);
        float s0 = 0, s1 = 0, s2 = 0, s3 = 0;
        for (int i = 0; i < D_ / 4; ++i) {
            float4 v = r[i];
            s0 = fmaf(v.x, v.x, s0); s1 = fmaf(v.y, v.y, s1);
            s2 = fmaf(v.z, v.z, s2); s3 = fmaf(v.w, v.w, s3);
        }
        sqT[n] = (s0 + s1) + (s2 + s3);
    }
}

// one thread per (m,n): dist -> Poisson weights -> psum[l] = sum_j w_j Q[j][l]
__global__ __launch_bounds__(256)
void k_main(const float* __restrict__ Xg, const float* __restrict__ TXg,
            char* __restrict__ ws) {
    const float* Q   = (const float*)(ws + OFF_Q);
    const float* lg  = (const float*)(ws + OFF_LG);
    const float* sqX = (const float*)(ws + OFF_SQX);
    const float* sqT = (const float*)(ws + OFF_SQT);
    float* psum      = (float*)(ws + OFF_PSUM);

    int r = blockIdx.x * 256 + threadIdx.x;      // row = m*N_+n ; m uniform per wave
    int m = r >> 11, n = r & (N_ - 1);

    const float4* X4 = (const float4*)(Xg + m * D_);   // wave-uniform -> s_load
    const float4* T4 = (const float4*)(TXg + n * D_);
    float d0 = 0, d1 = 0, d2 = 0, d3 = 0;
#pragma unroll 8
    for (int i = 0; i < D_ / 4; ++i) {
        float4 a = X4[i], b = T4[i];
        d0 = fmaf(a.x, b.x, d0); d1 = fmaf(a.y, b.y, d1);
        d2 = fmaf(a.z, b.z, d2); d3 = fmaf(a.w, b.w, d3);
    }
    float dot  = (d0 + d1) + (d2 + d3);
    float dist = fmaxf(sqX[m] + sqT[n] - 2.f * dot, 0.f);
    float lam  = 0.125f * dist;                  // half_nc
    float lnl  = __logf(lam);

    float acc[64];
#pragma unroll
    for (int l = 0; l < 64; ++l) acc[l] = 0.f;

    float jf = 0.f;
    for (int j = 0; j < J_; ++j) {
        float logw = fmaf(jf, lnl, -lam) - lg[j];   // lg[j] wave-uniform -> SGPR
        jf += 1.f;
        if (!__any(logw > -95.f)) continue;         // all lanes' w underflow -> skip
        float w = __expf(logw);
        const float* Qj = Q + (j << 6);             // wave-uniform -> s_load x64
#pragma unroll
        for (int l = 0; l < 64; ++l) acc[l] = fmaf(w, Qj[l], acc[l]);
    }

    float* out = psum + (size_t)r * 64;             // layout [m][n][l]
#pragma unroll
    for (int l4 = 0; l4 < 16; ++l4)
        ((float4*)out)[l4] = make_float4(acc[4 * l4], acc[4 * l4 + 1],
                                         acc[4 * l4 + 2], acc[4 * l4 + 3]);
}

// pass 1: per (m,chunk): sum over chunk of log(max(psum,1e-30)), per l
__global__ __launch_bounds__(64)
void k_chunksum(char* __restrict__ ws) {
    const float* psum = (const float*)(ws + OFF_PSUM);
    double* chunks    = (double*)(ws + OFF_CHUNK);
    int b = blockIdx.x, m = b >> 4, c = b & (CHUNKS - 1), l = threadIdx.x;
    const float* P = psum + (((size_t)m * N_ + (size_t)c * CN) << 6) + l;
    double s = 0.0;
    for (int i = 0; i < CN; ++i)
        s += (double)__logf(fmaxf(P[(size_t)i << 6], 1e-30f));
    chunks[(m * CHUNKS + c) * 64 + l] = s;
}

// exclusive prefix over chunks, per (m,l)
__global__ __launch_bounds__(256)
void k_prefix(char* __restrict__ ws) {
    const double* chunks = (const double*)(ws + OFF_CHUNK);
    double* offs         = (double*)(ws + OFF_OFFS);
    double* tot          = (double*)(ws + OFF_TOT);
    int idx = blockIdx.x * 256 + threadIdx.x;   // 4096 = M_*64
    int m = idx >> 6, l = idx & 63;
    double s = 0.0;
    for (int c = 0; c < CHUNKS; ++c) {
        offs[(m * CHUNKS + c) * 64 + l] = s;
        s += chunks[(m * CHUNKS + c) * 64 + l];
    }
    tot[m * 64 + l] = s;
}

// pass 2: running scan; p[m,n] contributions accumulated per class
__global__ __launch_bounds__(64)
void k_scan(const int* __restrict__ ty, char* __restrict__ ws) {
    const float* psum  = (const float*)(ws + OFF_PSUM);
    const double* offs = (const double*)(ws + OFF_OFFS);
    const double* tot  = (const double*)(ws + OFF_TOT);
    float* pred        = (float*)(ws + OFF_PRED);
    int b = blockIdx.x, m = b >> 4, c = b & (CHUNKS - 1), l = threadIdx.x;

    double cum = offs[(m * CHUNKS + c) * 64 + l];   // inclusive cum up to n0-1
    double T   = tot[m * 64 + l];
    const float* P = psum + (((size_t)m * N_ + (size_t)c * CN) << 6);
    int n0 = c * CN;
    float a0 = 0.f, a1 = 0.f;
    for (int i = 0; i < CN; ++i) {
        float pv = P[((size_t)i << 6) + l];
        float lv = __logf(fmaxf(pv, 1e-30f));
        double nbr = __shfl_down(cum, 1);           // cum[n-1, l+1]
        float pvn  = __shfl_down(pv, 1);            // psum[n, l+1]
        double cin = cum + (double)lv;              // cum[n, l]
        int n = n0 + i;
        double t1 = (n == 0) ? 0.0 : ((l == 63) ? -999999.0 : nbr);
        double t2 = T - cin;
        float e = (float)(t1 + t2);
        float pm = (l == 63) ? pv : (pv - pvn);
        float contrib = pm * __expf(e);
        int y = ty[n];                               // wave-uniform
        a0 += (y == 0) ? contrib : 0.f;
        a1 += (y == 1) ? contrib : 0.f;
        cum = cin;
    }
#pragma unroll
    for (int o = 32; o > 0; o >>= 1) {
        a0 += __shfl_down(a0, o);
        a1 += __shfl_down(a1, o);
    }
    if (l == 0) {
        atomicAdd(&pred[m * 2 + 0], a0);
        atomicAdd(&pred[m * 2 + 1], a1);
    }
}

__global__ __launch_bounds__(64)
void k_norm(char* __restrict__ ws, float* __restrict__ out) {
    const float* pred = (const float*)(ws + OFF_PRED);
    int m = threadIdx.x;
    float a = pred[2 * m], b = pred[2 * m + 1];
    float s = a + b;
    out[2 * m]     = a / s;
    out[2 * m + 1] = b / s;
}

extern "C" void kernel_launch(void* const* d_in, const int* in_sizes, int n_in,
                              void* d_out, int out_size, void* d_ws, size_t ws_size,
                              hipStream_t stream) {
    const float* X       = (const float*)d_in[0];
    const float* train_X = (const float*)d_in[1];
    const float* buckets = (const float*)d_in[2];
    const int*   train_y = (const int*)d_in[3];
    float* out = (float*)d_out;
    char*  ws  = (char*)d_ws;

    k_setup<<<1, 512, 0, stream>>>(buckets, ws);
    k_sq<<<(M_ + N_ + 255) / 256, 256, 0, stream>>>(X, train_X, ws);
    k_main<<<(M_ * N_) / 256, 256, 0, stream>>>(X, train_X, ws);
    k_chunksum<<<M_ * CHUNKS, 64, 0, stream>>>(ws);
    k_prefix<<<(M_ * 64) / 256, 256, 0, stream>>>(ws);
    k_scan<<<M_ * CHUNKS, 64, 0, stream>>>(train_y, ws);
    k_norm<<<1, 64, 0, stream>>>(ws, out);
}

// Round 3
// 246.029 us; speedup vs baseline: 1.4720x; 1.4720x over previous
//
#include <hip/hip_runtime.h>
#include <math.h>

#define M_ 64
#define N_ 2048
#define D_ 256
#define L_ 64
#define J_ 384
#define CHUNKS 32
#define CN 64   // N_/CHUNKS

// ---- ws byte offsets ----
#define OFF_Q     0u          // [J_][64] f32 : 98304
#define OFF_LG    98304u      // [J_] f32     : 1536
#define OFF_PRED  99840u      // [M_*2] f32   : 512
#define OFF_DIST  100352u     // [M_][N_] f32 : 524288
#define OFF_CHUNK 624640u     // [M_][CHUNKS][64] double : 1048576 (prefix done in-place)
#define OFF_TOT   1673216u    // [M_][64] double : 32768
#define OFF_PSUM  1705984u    // [M_*N_][64] f32 : 33554432  (total ~35.3 MB)

__global__ __launch_bounds__(512)
void k_setup(const float* __restrict__ buckets, char* __restrict__ ws) {
    float* Q    = (float*)(ws + OFF_Q);
    float* lg   = (float*)(ws + OFF_LG);
    float* pred = (float*)(ws + OFF_PRED);
    int t = threadIdx.x;
    if (t < 64) {
        // x_l = 0.5 * buckets[l] / SIGMA2 = buckets[l]/8
        double x = (double)buckets[t] * 0.125;
        const double a0 = 128.0;   // 0.5*D
        double gln = lgamma(a0);
        double q;
        if (x < a0 + 1.0) {
            double ap = a0, sum = 1.0 / a0, del = sum;
            for (int it = 0; it < 4000; ++it) {
                ap += 1.0; del *= x / ap; sum += del;
                if (fabs(del) < fabs(sum) * 1e-17) break;
            }
            q = 1.0 - sum * exp(-x + a0 * log(x) - gln);
        } else {
            double b = x + 1.0 - a0, c = 1e300, d = 1.0 / b, h = d;
            for (int i = 1; i <= 4000; ++i) {
                double an = -(double)i * ((double)i - a0);
                b += 2.0;
                d = an * d + b; if (fabs(d) < 1e-300) d = 1e-300;
                c = b + an / c; if (fabs(c) < 1e-300) c = 1e-300;
                d = 1.0 / d;
                double delc = d * c; h *= delc;
                if (fabs(delc - 1.0) < 1e-16) break;
            }
            q = exp(-x + a0 * log(x) - gln) * h;
        }
        double tt = exp(a0 * log(x) - x - lgamma(a0 + 1.0));
        for (int j = 0; j < J_; ++j) {
            Q[j * 64 + t] = (float)q;
            q += tt; if (q > 1.0) q = 1.0;
            tt *= x / (a0 + (double)j + 1.0);
        }
    } else if (t < 64 + J_) {
        int j = t - 64;
        lg[j] = (float)lgamma((double)(j + 1));
    } else if (t < 64 + J_ + 64) {
        int i = t - (64 + J_);
        pred[2 * i] = 0.f; pred[2 * i + 1] = 0.f;
    }
}

// dist[m][n] = max(|X_m|^2 + |T_n|^2 - 2 X_m.T_n, 0)
__global__ __launch_bounds__(256)
void k_dist(const float* __restrict__ Xg, const float* __restrict__ TXg,
            float* __restrict__ dist) {
    int r = blockIdx.x * 256 + threadIdx.x;   // m uniform per block (8 blocks/m)
    int m = r >> 11, n = r & (N_ - 1);
    const float4* X4 = (const float4*)(Xg + m * D_);
    const float4* T4 = (const float4*)(TXg + n * D_);
    float d0 = 0, d1 = 0, d2 = 0, d3 = 0;
    float x0 = 0, x1 = 0, x2 = 0, x3 = 0;
    float t0 = 0, t1 = 0, t2 = 0, t3 = 0;
#pragma unroll 8
    for (int i = 0; i < D_ / 4; ++i) {
        float4 a = X4[i], b = T4[i];
        d0 = fmaf(a.x, b.x, d0); d1 = fmaf(a.y, b.y, d1);
        d2 = fmaf(a.z, b.z, d2); d3 = fmaf(a.w, b.w, d3);
        x0 = fmaf(a.x, a.x, x0); x1 = fmaf(a.y, a.y, x1);
        x2 = fmaf(a.z, a.z, x2); x3 = fmaf(a.w, a.w, x3);
        t0 = fmaf(b.x, b.x, t0); t1 = fmaf(b.y, b.y, t1);
        t2 = fmaf(b.z, b.z, t2); t3 = fmaf(b.w, b.w, t3);
    }
    float dot = (d0 + d1) + (d2 + d3);
    float sx  = (x0 + x1) + (x2 + x3);
    float st  = (t0 + t1) + (t2 + t3);
    dist[r] = fmaxf(sx + st - 2.f * dot, 0.f);
}

// thread = (m, n, l-quarter); wave = 64 n for one (m,lq) -> Q slice wave-uniform
__global__ __launch_bounds__(256)
void k_main(const float* __restrict__ Q, const float* __restrict__ lg,
            const float* __restrict__ dist, float* __restrict__ psum) {
    int b = blockIdx.x;                 // 2048 = m*32 + c
    int m = b >> 5, c = b & 31;
    int t = threadIdx.x;
    int nloc = t & 63;
    int lq = __builtin_amdgcn_readfirstlane(t >> 6);
    int n = (c << 6) + nloc;

    float d    = dist[(m << 11) + n];   // coalesced
    float lam  = 0.125f * d;
    float nlam = -lam;
    float lnl  = __logf(lam);

    float4 a0 = {0,0,0,0}, a1 = {0,0,0,0}, a2 = {0,0,0,0}, a3 = {0,0,0,0};
    const float4* Qb = (const float4*)(Q + (lq << 4));   // wave-uniform base

    float jf = 0.f;
    for (int j = 0; j < J_; ++j) {
        float logw = fmaf(jf, lnl, nlam) - lg[j];   // lg[j]: SGPR
        jf += 1.f;
        if (__any(logw > -95.f)) {
            float w = __expf(logw);
            float4 q0 = Qb[(j << 4) + 0];           // wave-uniform -> s_load
            float4 q1 = Qb[(j << 4) + 1];
            float4 q2 = Qb[(j << 4) + 2];
            float4 q3 = Qb[(j << 4) + 3];
            a0.x = fmaf(w, q0.x, a0.x); a0.y = fmaf(w, q0.y, a0.y);
            a0.z = fmaf(w, q0.z, a0.z); a0.w = fmaf(w, q0.w, a0.w);
            a1.x = fmaf(w, q1.x, a1.x); a1.y = fmaf(w, q1.y, a1.y);
            a1.z = fmaf(w, q1.z, a1.z); a1.w = fmaf(w, q1.w, a1.w);
            a2.x = fmaf(w, q2.x, a2.x); a2.y = fmaf(w, q2.y, a2.y);
            a2.z = fmaf(w, q2.z, a2.z); a2.w = fmaf(w, q2.w, a2.w);
            a3.x = fmaf(w, q3.x, a3.x); a3.y = fmaf(w, q3.y, a3.y);
            a3.z = fmaf(w, q3.z, a3.z); a3.w = fmaf(w, q3.w, a3.w);
        } else if (__all(jf > lam)) {
            break;   // past Poisson peak everywhere and fully underflowed
        }
    }
    float* out = psum + (((size_t)(m << 11) + n) << 6) + (lq << 4);
    ((float4*)out)[0] = a0;
    ((float4*)out)[1] = a1;
    ((float4*)out)[2] = a2;
    ((float4*)out)[3] = a3;
}

// per (m,chunk): sum over chunk of log(max(psum,1e-30)), per l (lane=l)
__global__ __launch_bounds__(64)
void k_chunksum(char* __restrict__ ws) {
    const float* psum = (const float*)(ws + OFF_PSUM);
    double* chunks    = (double*)(ws + OFF_CHUNK);
    int b = blockIdx.x, m = b >> 5, c = b & (CHUNKS - 1), l = threadIdx.x;
    const float* P = psum + (((size_t)m * N_ + (size_t)c * CN) << 6) + l;
    double s = 0.0;
#pragma unroll 8
    for (int i = 0; i < CN; ++i)
        s += (double)__logf(fmaxf(P[(size_t)i << 6], 1e-30f));
    chunks[(m * CHUNKS + c) * 64 + l] = s;
}

// exclusive prefix over chunks, in place; per (m,l)
__global__ __launch_bounds__(256)
void k_prefix(char* __restrict__ ws) {
    double* chunks = (double*)(ws + OFF_CHUNK);
    double* tot    = (double*)(ws + OFF_TOT);
    int idx = blockIdx.x * 256 + threadIdx.x;   // 4096 = M_*64
    int m = idx >> 6, l = idx & 63;
    double s = 0.0;
    for (int c = 0; c < CHUNKS; ++c) {
        int slot = (m * CHUNKS + c) * 64 + l;
        double v = chunks[slot];
        chunks[slot] = s;       // exclusive prefix
        s += v;
    }
    tot[m * 64 + l] = s;
}

// pass 2: running scan; p[m,n] contributions accumulated per class
__global__ __launch_bounds__(64)
void k_scan(const int* __restrict__ ty, char* __restrict__ ws) {
    const float* psum  = (const float*)(ws + OFF_PSUM);
    const double* offs = (const double*)(ws + OFF_CHUNK);  // now exclusive prefixes
    const double* tot  = (const double*)(ws + OFF_TOT);
    float* pred        = (float*)(ws + OFF_PRED);
    int b = blockIdx.x, m = b >> 5, c = b & (CHUNKS - 1), l = threadIdx.x;

    double cum = offs[(m * CHUNKS + c) * 64 + l];   // inclusive cum up to n0-1
    double T   = tot[m * 64 + l];
    const float* P = psum + (((size_t)m * N_ + (size_t)c * CN) << 6);
    int n0 = c * CN;
    float a0 = 0.f, a1 = 0.f;
    for (int i = 0; i < CN; ++i) {
        float pv = P[((size_t)i << 6) + l];
        float lv = __logf(fmaxf(pv, 1e-30f));
        double nbr = __shfl_down(cum, 1);           // cum[n-1, l+1]
        float pvn  = __shfl_down(pv, 1);            // psum[n, l+1]
        double cin = cum + (double)lv;              // cum[n, l]
        int n = n0 + i;
        double t1 = (n == 0) ? 0.0 : ((l == 63) ? -999999.0 : nbr);
        double t2 = T - cin;
        float e = (float)(t1 + t2);
        float pm = (l == 63) ? pv : (pv - pvn);
        float contrib = pm * __expf(e);
        int y = ty[n];                               // wave-uniform
        a0 += (y == 0) ? contrib : 0.f;
        a1 += (y == 1) ? contrib : 0.f;
        cum = cin;
    }
#pragma unroll
    for (int o = 32; o > 0; o >>= 1) {
        a0 += __shfl_down(a0, o);
        a1 += __shfl_down(a1, o);
    }
    if (l == 0) {
        atomicAdd(&pred[m * 2 + 0], a0);
        atomicAdd(&pred[m * 2 + 1], a1);
    }
}

__global__ __launch_bounds__(64)
void k_norm(char* __restrict__ ws, float* __restrict__ out) {
    const float* pred = (const float*)(ws + OFF_PRED);
    int m = threadIdx.x;
    float a = pred[2 * m], b = pred[2 * m + 1];
    float s = a + b;
    out[2 * m]     = a / s;
    out[2 * m + 1] = b / s;
}

extern "C" void kernel_launch(void* const* d_in, const int* in_sizes, int n_in,
                              void* d_out, int out_size, void* d_ws, size_t ws_size,
                              hipStream_t stream) {
    const float* X       = (const float*)d_in[0];
    const float* train_X = (const float*)d_in[1];
    const float* buckets = (const float*)d_in[2];
    const int*   train_y = (const int*)d_in[3];
    float* out = (float*)d_out;
    char*  ws  = (char*)d_ws;

    float* Qp    = (float*)(ws + OFF_Q);
    float* lgp   = (float*)(ws + OFF_LG);
    float* distp = (float*)(ws + OFF_DIST);
    float* psump = (float*)(ws + OFF_PSUM);

    k_setup<<<1, 512, 0, stream>>>(buckets, ws);
    k_dist<<<(M_ * N_) / 256, 256, 0, stream>>>(X, train_X, distp);
    k_main<<<M_ * CHUNKS, 256, 0, stream>>>(Qp, lgp, distp, psump);
    k_chunksum<<<M_ * CHUNKS, 64, 0, stream>>>(ws);
    k_prefix<<<(M_ * 64) / 256, 256, 0, stream>>>(ws);
    k_scan<<<M_ * CHUNKS, 64, 0, stream>>>(train_y, ws);
    k_norm<<<1, 64, 0, stream>>>(ws, out);
}

// Round 4
// 203.713 us; speedup vs baseline: 1.7778x; 1.2077x over previous
//
#include <hip/hip_runtime.h>
#include <math.h>

#define M_ 64
#define N_ 2048
#define D_ 256
#define L_ 64
#define J_ 384
#define CHUNKS 32
#define CN 64   // N_/CHUNKS

typedef _Float16 half8 __attribute__((ext_vector_type(8)));
typedef float f32x4 __attribute__((ext_vector_type(4)));

// ---- ws byte offsets ----
#define OFF_F16   0u          // [64 l][384 j] f16 CDF table : 49152
#define OFF_LG8   49152u      // [48] f32 lgamma(8i+1) : 192
#define OFF_INV   49344u      // [384] f32 1/(i+1) : 1536
#define OFF_SQX   50880u      // [64] f32
#define OFF_PRED  51136u      // [128] f32
#define OFF_DIST  51712u      // [64][2048] f32 : 524288
#define OFF_CHUNK 576000u     // [64][32][64] f64 : 1048576
#define OFF_TOT   1624576u    // [64][64] f64 : 32768
#define OFF_PSUM  1657344u    // [64*2048][64] f32 : 33554432 (total ~35.2 MB)

__global__ __launch_bounds__(512)
void k_setup(const float* __restrict__ buckets, const float* __restrict__ Xg,
             char* __restrict__ ws) {
    _Float16* F16 = (_Float16*)(ws + OFF_F16);
    float* lg8  = (float*)(ws + OFF_LG8);
    float* invt = (float*)(ws + OFF_INV);
    float* sqX  = (float*)(ws + OFF_SQX);
    float* pred = (float*)(ws + OFF_PRED);
    int t = threadIdx.x;
    if (t < 64) {
        // x_l = 0.5 * buckets[l] / SIGMA2 = buckets[l]/8
        double x = (double)buckets[t] * 0.125;
        const double a0 = 128.0;   // 0.5*D
        double gln = lgamma(a0);
        double q;
        if (x < a0 + 1.0) {
            double ap = a0, sum = 1.0 / a0, del = sum;
            for (int it = 0; it < 4000; ++it) {
                ap += 1.0; del *= x / ap; sum += del;
                if (fabs(del) < fabs(sum) * 1e-17) break;
            }
            q = 1.0 - sum * exp(-x + a0 * log(x) - gln);
        } else {
            double b = x + 1.0 - a0, c = 1e300, d = 1.0 / b, h = d;
            for (int i = 1; i <= 4000; ++i) {
                double an = -(double)i * ((double)i - a0);
                b += 2.0;
                d = an * d + b; if (fabs(d) < 1e-300) d = 1e-300;
                c = b + an / c; if (fabs(c) < 1e-300) c = 1e-300;
                d = 1.0 / d;
                double delc = d * c; h *= delc;
                if (fabs(delc - 1.0) < 1e-16) break;
            }
            q = exp(-x + a0 * log(x) - gln) * h;
        }
        double tt = exp(a0 * log(x) - x - lgamma(a0 + 1.0));
        // F[j] = CDF = 1 - Q(a0+j, x);  row-major [l][j]
        for (int j = 0; j < J_; ++j) {
            double F = 1.0 - q;
            if (F < 0.0) F = 0.0;
            F16[t * J_ + j] = (_Float16)F;
            q += tt; if (q > 1.0) q = 1.0;
            tt *= x / (a0 + (double)j + 1.0);
        }
    } else if (t < 128) {
        int i = t - 64;
        const float4* xr = (const float4*)(Xg + i * D_);
        float s0 = 0, s1 = 0, s2 = 0, s3 = 0;
        for (int k = 0; k < D_ / 4; ++k) {
            float4 v = xr[k];
            s0 = fmaf(v.x, v.x, s0); s1 = fmaf(v.y, v.y, s1);
            s2 = fmaf(v.z, v.z, s2); s3 = fmaf(v.w, v.w, s3);
        }
        sqX[i] = (s0 + s1) + (s2 + s3);
        if (i < 48) lg8[i] = (float)lgamma(8.0 * (double)i + 1.0);
        else { int p = i - 48; for (int e = 0; e < 8; ++e) pred[8 * p + e] = 0.f; }
    } else {
        int i = t - 128;   // 0..383
        invt[i] = 1.0f / (float)(i + 1);
    }
}

// dist[m][n]; thread = (4 m, 1 n); T row reused in regs across 4 m
__global__ __launch_bounds__(256)
void k_dist(const float* __restrict__ Xg, const float* __restrict__ TXg,
            char* __restrict__ ws) {
    const float* sqX = (const float*)(ws + OFF_SQX);
    float* dist      = (float*)(ws + OFF_DIST);
    int bid = blockIdx.x;                 // 128 = 16 m-groups x 8 n-blocks
    int n  = ((bid & 7) << 8) + threadIdx.x;
    int mg = (bid >> 3) << 2;             // wave-uniform
    const float4* T4 = (const float4*)(TXg + (size_t)n * D_);
    const float4* X4 = (const float4*)Xg;
    float4 a0{0,0,0,0}, a1{0,0,0,0}, a2{0,0,0,0}, a3{0,0,0,0}, st{0,0,0,0};
#pragma unroll 8
    for (int k = 0; k < D_ / 4; ++k) {
        float4 tv = T4[k];
        st.x = fmaf(tv.x, tv.x, st.x); st.y = fmaf(tv.y, tv.y, st.y);
        st.z = fmaf(tv.z, tv.z, st.z); st.w = fmaf(tv.w, tv.w, st.w);
        float4 x0 = X4[(mg + 0) * 64 + k];
        a0.x = fmaf(x0.x, tv.x, a0.x); a0.y = fmaf(x0.y, tv.y, a0.y);
        a0.z = fmaf(x0.z, tv.z, a0.z); a0.w = fmaf(x0.w, tv.w, a0.w);
        float4 x1 = X4[(mg + 1) * 64 + k];
        a1.x = fmaf(x1.x, tv.x, a1.x); a1.y = fmaf(x1.y, tv.y, a1.y);
        a1.z = fmaf(x1.z, tv.z, a1.z); a1.w = fmaf(x1.w, tv.w, a1.w);
        float4 x2 = X4[(mg + 2) * 64 + k];
        a2.x = fmaf(x2.x, tv.x, a2.x); a2.y = fmaf(x2.y, tv.y, a2.y);
        a2.z = fmaf(x2.z, tv.z, a2.z); a2.w = fmaf(x2.w, tv.w, a2.w);
        float4 x3 = X4[(mg + 3) * 64 + k];
        a3.x = fmaf(x3.x, tv.x, a3.x); a3.y = fmaf(x3.y, tv.y, a3.y);
        a3.z = fmaf(x3.z, tv.z, a3.z); a3.w = fmaf(x3.w, tv.w, a3.w);
    }
    float stt = (st.x + st.y) + (st.z + st.w);
    float d0 = (a0.x + a0.y) + (a0.z + a0.w);
    float d1 = (a1.x + a1.y) + (a1.z + a1.w);
    float d2 = (a2.x + a2.y) + (a2.z + a2.w);
    float d3 = (a3.x + a3.y) + (a3.z + a3.w);
    dist[(mg + 0) * N_ + n] = fmaxf(sqX[mg + 0] + stt - 2.f * d0, 0.f);
    dist[(mg + 1) * N_ + n] = fmaxf(sqX[mg + 1] + stt - 2.f * d1, 0.f);
    dist[(mg + 2) * N_ + n] = fmaxf(sqX[mg + 2] + stt - 2.f * d2, 0.f);
    dist[(mg + 3) * N_ + n] = fmaxf(sqX[mg + 3] + stt - 2.f * d3, 0.f);
}

// R[m,n,l] = sum_j w_j F16[l][j] via f16 MFMA; psum = 1-R; fused chunk log-sums.
// block = 128 thr = 2 waves; block tile = 64 n (one chunk) x 64 l; K = 384.
// wave owns 32 rows = 2 strips of 16. A generated in-register (Poisson weights).
__global__ __launch_bounds__(128)
void k_mfma(char* __restrict__ ws) {
    const float* dist     = (const float*)(ws + OFF_DIST);
    const _Float16* F16   = (const _Float16*)(ws + OFF_F16);
    const float* lg8      = (const float*)(ws + OFF_LG8);
    const float* invt     = (const float*)(ws + OFF_INV);
    float* psum           = (float*)(ws + OFF_PSUM);
    double* chunk         = (double*)(ws + OFF_CHUNK);

    __shared__ double s_part[2][64];

    int bid = blockIdx.x;            // 2048 = m*32 + c
    int m = bid >> 5, c = bid & 31;
    int n0 = c << 6;
    int t = threadIdx.x;
    int w = t >> 6, l = t & 63;
    int col = l & 15, g = l >> 4;
    int rbase = n0 + (w << 5);       // wave rows rbase..rbase+31 (global n)

    const float* drow = dist + (m << 11);
    float la0 = drow[rbase + col];          // strip 0 row = col
    float la1 = drow[rbase + 16 + col];     // strip 1
    la0 *= 0.125f; la1 *= 0.125f;           // lambda = dist/8
    float ll0 = __logf(la0), ll1 = __logf(la1);

    f32x4 acc00 = {0,0,0,0}, acc01 = {0,0,0,0}, acc02 = {0,0,0,0}, acc03 = {0,0,0,0};
    f32x4 acc10 = {0,0,0,0}, acc11 = {0,0,0,0}, acc12 = {0,0,0,0}, acc13 = {0,0,0,0};

    for (int s = 0; s < 12; ++s) {
        int jb = (s << 5) + (g << 3);       // lane's k-base this step
        float jbf = (float)jb;
        // B fragments: F16[colg][jb..jb+7], contiguous 16B
        half8 b0 = *(const half8*)(F16 + (size_t)(col     ) * J_ + jb);
        half8 b1 = *(const half8*)(F16 + (size_t)(col + 16) * J_ + jb);
        half8 b2 = *(const half8*)(F16 + (size_t)(col + 32) * J_ + jb);
        half8 b3 = *(const half8*)(F16 + (size_t)(col + 48) * J_ + jb);
        float lgv = lg8[(s << 2) + g];      // lgamma(jb+1)
        float4 iv0 = *(const float4*)(invt + jb);       // 1/(jb+1..jb+4)
        float4 iv1 = *(const float4*)(invt + jb + 4);   // 1/(jb+5..jb+8)
        // ---- strip 0: A from Poisson weights of row (col) ----
        {
            float wv = __expf(fmaf(jbf, ll0, -la0 - lgv));
            half8 a;
            a[0] = (_Float16)wv;
            wv *= la0 * iv0.x; a[1] = (_Float16)wv;
            wv *= la0 * iv0.y; a[2] = (_Float16)wv;
            wv *= la0 * iv0.z; a[3] = (_Float16)wv;
            wv *= la0 * iv0.w; a[4] = (_Float16)wv;
            wv *= la0 * iv1.x; a[5] = (_Float16)wv;
            wv *= la0 * iv1.y; a[6] = (_Float16)wv;
            wv *= la0 * iv1.z; a[7] = (_Float16)wv;
            acc00 = __builtin_amdgcn_mfma_f32_16x16x32_f16(a, b0, acc00, 0, 0, 0);
            acc01 = __builtin_amdgcn_mfma_f32_16x16x32_f16(a, b1, acc01, 0, 0, 0);
            acc02 = __builtin_amdgcn_mfma_f32_16x16x32_f16(a, b2, acc02, 0, 0, 0);
            acc03 = __builtin_amdgcn_mfma_f32_16x16x32_f16(a, b3, acc03, 0, 0, 0);
        }
        // ---- strip 1 ----
        {
            float wv = __expf(fmaf(jbf, ll1, -la1 - lgv));
            half8 a;
            a[0] = (_Float16)wv;
            wv *= la1 * iv0.x; a[1] = (_Float16)wv;
            wv *= la1 * iv0.y; a[2] = (_Float16)wv;
            wv *= la1 * iv0.z; a[3] = (_Float16)wv;
            wv *= la1 * iv0.w; a[4] = (_Float16)wv;
            wv *= la1 * iv1.x; a[5] = (_Float16)wv;
            wv *= la1 * iv1.y; a[6] = (_Float16)wv;
            wv *= la1 * iv1.z; a[7] = (_Float16)wv;
            acc10 = __builtin_amdgcn_mfma_f32_16x16x32_f16(a, b0, acc10, 0, 0, 0);
            acc11 = __builtin_amdgcn_mfma_f32_16x16x32_f16(a, b1, acc11, 0, 0, 0);
            acc12 = __builtin_amdgcn_mfma_f32_16x16x32_f16(a, b2, acc12, 0, 0, 0);
            acc13 = __builtin_amdgcn_mfma_f32_16x16x32_f16(a, b3, acc13, 0, 0, 0);
        }
    }

    // ---- epilogue: psi = 1-R, store, and per-chunk log-sums ----
    // C/D layout: col_local = l&15, row_local = g*4 + reg  (m89-verified)
    double lsum0 = 0.0, lsum1 = 0.0, lsum2 = 0.0, lsum3 = 0.0;
    float* pbase = psum + (((size_t)(m << 11) + rbase) << 6);
#define EPI(ACC, SP, TI, LS)                                                    \
    {                                                                           \
        _Pragma("unroll")                                                       \
        for (int r = 0; r < 4; ++r) {                                           \
            float ps = 1.f - (ACC)[r];                                          \
            int row = (SP) * 16 + g * 4 + r;                                    \
            pbase[((size_t)row << 6) + (TI) * 16 + col] = ps;                   \
            LS += (double)__logf(fmaxf(ps, 1e-30f));                            \
        }                                                                       \
    }
    EPI(acc00, 0, 0, lsum0) EPI(acc01, 0, 1, lsum1) EPI(acc02, 0, 2, lsum2) EPI(acc03, 0, 3, lsum3)
    EPI(acc10, 1, 0, lsum0) EPI(acc11, 1, 1, lsum1) EPI(acc12, 1, 2, lsum2) EPI(acc13, 1, 3, lsum3)
#undef EPI
    // reduce across g (lanes l^16, l^32): each lane then holds 32-row sum for its col
    lsum0 += __shfl_xor(lsum0, 16); lsum0 += __shfl_xor(lsum0, 32);
    lsum1 += __shfl_xor(lsum1, 16); lsum1 += __shfl_xor(lsum1, 32);
    lsum2 += __shfl_xor(lsum2, 16); lsum2 += __shfl_xor(lsum2, 32);
    lsum3 += __shfl_xor(lsum3, 16); lsum3 += __shfl_xor(lsum3, 32);
    if (g == 0) {
        s_part[w][col]      = lsum0;
        s_part[w][16 + col] = lsum1;
        s_part[w][32 + col] = lsum2;
        s_part[w][48 + col] = lsum3;
    }
    __syncthreads();
    if (t < 64)
        chunk[((m << 5) + c) * 64 + t] = s_part[0][t] + s_part[1][t];
}

// exclusive prefix over chunks, in place; per (m,l)
__global__ __launch_bounds__(256)
void k_prefix(char* __restrict__ ws) {
    double* chunks = (double*)(ws + OFF_CHUNK);
    double* tot    = (double*)(ws + OFF_TOT);
    int idx = blockIdx.x * 256 + threadIdx.x;   // 4096 = M_*64
    int m = idx >> 6, l = idx & 63;
    double s = 0.0;
    for (int c = 0; c < CHUNKS; ++c) {
        int slot = (m * CHUNKS + c) * 64 + l;
        double v = chunks[slot];
        chunks[slot] = s;       // exclusive prefix
        s += v;
    }
    tot[m * 64 + l] = s;
}

// pass 2: running scan; p[m,n] contributions accumulated per class
__global__ __launch_bounds__(64)
void k_scan(const int* __restrict__ ty, char* __restrict__ ws) {
    const float* psum  = (const float*)(ws + OFF_PSUM);
    const double* offs = (const double*)(ws + OFF_CHUNK);  // exclusive prefixes
    const double* tot  = (const double*)(ws + OFF_TOT);
    float* pred        = (float*)(ws + OFF_PRED);
    int b = blockIdx.x, m = b >> 5, c = b & (CHUNKS - 1), l = threadIdx.x;

    double cum = offs[(m * CHUNKS + c) * 64 + l];   // inclusive cum up to n0-1
    double T   = tot[m * 64 + l];
    const float* P = psum + (((size_t)m * N_ + (size_t)c * CN) << 6);
    int n0 = c * CN;
    float a0 = 0.f, a1 = 0.f;
    for (int i = 0; i < CN; ++i) {
        float pv = P[((size_t)i << 6) + l];
        float lv = __logf(fmaxf(pv, 1e-30f));
        double nbr = __shfl_down(cum, 1);           // cum[n-1, l+1]
        float pvn  = __shfl_down(pv, 1);            // psum[n, l+1]
        double cin = cum + (double)lv;              // cum[n, l]
        int n = n0 + i;
        double t1 = (n == 0) ? 0.0 : ((l == 63) ? -999999.0 : nbr);
        double t2 = T - cin;
        float e = (float)(t1 + t2);
        float pm = (l == 63) ? pv : (pv - pvn);
        float contrib = pm * __expf(e);
        int y = ty[n];                               // wave-uniform
        a0 += (y == 0) ? contrib : 0.f;
        a1 += (y == 1) ? contrib : 0.f;
        cum = cin;
    }
#pragma unroll
    for (int o = 32; o > 0; o >>= 1) {
        a0 += __shfl_down(a0, o);
        a1 += __shfl_down(a1, o);
    }
    if (l == 0) {
        atomicAdd(&pred[m * 2 + 0], a0);
        atomicAdd(&pred[m * 2 + 1], a1);
    }
}

__global__ __launch_bounds__(64)
void k_norm(char* __restrict__ ws, float* __restrict__ out) {
    const float* pred = (const float*)(ws + OFF_PRED);
    int m = threadIdx.x;
    float a = pred[2 * m], b = pred[2 * m + 1];
    float s = a + b;
    out[2 * m]     = a / s;
    out[2 * m + 1] = b / s;
}

extern "C" void kernel_launch(void* const* d_in, const int* in_sizes, int n_in,
                              void* d_out, int out_size, void* d_ws, size_t ws_size,
                              hipStream_t stream) {
    const float* X       = (const float*)d_in[0];
    const float* train_X = (const float*)d_in[1];
    const float* buckets = (const float*)d_in[2];
    const int*   train_y = (const int*)d_in[3];
    float* out = (float*)d_out;
    char*  ws  = (char*)d_ws;

    k_setup<<<1, 512, 0, stream>>>(buckets, X, ws);
    k_dist<<<128, 256, 0, stream>>>(X, train_X, ws);
    k_mfma<<<M_ * CHUNKS, 128, 0, stream>>>(ws);
    k_prefix<<<(M_ * 64) / 256, 256, 0, stream>>>(ws);
    k_scan<<<M_ * CHUNKS, 64, 0, stream>>>(train_y, ws);
    k_norm<<<1, 64, 0, stream>>>(ws, out);
}

// Round 5
// 168.104 us; speedup vs baseline: 2.1544x; 1.2118x over previous
//
#include <hip/hip_runtime.h>
#include <math.h>

#define M_ 64
#define N_ 2048
#define D_ 256
#define L_ 64
#define J_ 384
#define CHUNKS 32
#define CN 64   // N_/CHUNKS

typedef _Float16 half8 __attribute__((ext_vector_type(8)));
typedef float f32x4 __attribute__((ext_vector_type(4)));

// ---- ws byte offsets ----
#define OFF_F16   0u          // [64 l][384 j] f16 CDF table : 49152
#define OFF_LG8   49152u      // [48] f32 lgamma(8i+1) : 192
#define OFF_INV   49344u      // [384] f32 1/(i+1) : 1536
#define OFF_SQX   50880u      // [64] f32
#define OFF_PRED  51136u      // [128] f32
#define OFF_CHUNK 576000u     // [64][32][64] f64 : 1048576
#define OFF_PSUM  1657344u    // [64*2048][64] f32 : 33554432 (total ~35.2 MB)

// blocks 0..11: F16[l][jg*32 .. jg*32+31] from an independent gammainc start
// block 12: sqX, lg8, invt, pred-zero
__global__ __launch_bounds__(64)
void k_tab(const float* __restrict__ buckets, const float* __restrict__ Xg,
           char* __restrict__ ws) {
    _Float16* F16 = (_Float16*)(ws + OFF_F16);
    float* lg8  = (float*)(ws + OFF_LG8);
    float* invt = (float*)(ws + OFF_INV);
    float* sqX  = (float*)(ws + OFF_SQX);
    float* pred = (float*)(ws + OFF_PRED);
    int jg = blockIdx.x, l = threadIdx.x;

    if (jg < 12) {
        double x = (double)buckets[l] * 0.125;       // 0.5*bucket/SIGMA2
        double a = 128.0 + 32.0 * (double)jg;        // 0.5*D + jg*32
        double gln = lgamma(a);
        double q;                                    // Q(a, x) upper regularized
        if (x < a + 1.0) {
            double ap = a, sum = 1.0 / a, del = sum;
            for (int it = 0; it < 3000; ++it) {
                ap += 1.0; del *= x / ap; sum += del;
                if (fabs(del) < fabs(sum) * 1e-16) break;
            }
            q = 1.0 - sum * exp(-x + a * log(x) - gln);
        } else {
            double b = x + 1.0 - a, c = 1e300, d = 1.0 / b, h = d;
            for (int i = 1; i <= 3000; ++i) {
                double an = -(double)i * ((double)i - a);
                b += 2.0;
                d = an * d + b; if (fabs(d) < 1e-300) d = 1e-300;
                c = b + an / c; if (fabs(c) < 1e-300) c = 1e-300;
                d = 1.0 / d;
                double delc = d * c; h *= delc;
                if (fabs(delc - 1.0) < 1e-16) break;
            }
            q = exp(-x + a * log(x) - gln) * h;
        }
        double tt = exp(a * log(x) - x - lgamma(a + 1.0));  // pmf term at a
        for (int jj = 0; jj < 32; ++jj) {
            double F = 1.0 - q;                      // CDF = P(a+jj, x)
            if (F < 0.0) F = 0.0;
            F16[l * J_ + (jg << 5) + jj] = (_Float16)F;
            q += tt; if (q > 1.0) q = 1.0;
            tt *= x / (a + (double)jj + 1.0);
        }
    } else {
        // housekeeping
        const float4* xr = (const float4*)(Xg + l * D_);
        float s0 = 0, s1 = 0, s2 = 0, s3 = 0;
        for (int k = 0; k < D_ / 4; ++k) {
            float4 v = xr[k];
            s0 = fmaf(v.x, v.x, s0); s1 = fmaf(v.y, v.y, s1);
            s2 = fmaf(v.z, v.z, s2); s3 = fmaf(v.w, v.w, s3);
        }
        sqX[l] = (s0 + s1) + (s2 + s3);
        if (l < 48) lg8[l] = (float)lgamma(8.0 * (double)l + 1.0);
        for (int i = l; i < J_; i += 64) invt[i] = 1.0f / (float)(i + 1);
        pred[2 * l] = 0.f; pred[2 * l + 1] = 0.f;
    }
}

// Fused: dist prologue + R = sum_j w_j F16[l][j] via f16 MFMA + chunk log-sums.
// block = 128 thr = 2 waves; tile = 64 n (one chunk) x 64 l; K = 384.
__global__ __launch_bounds__(128)
void k_fused(const float* __restrict__ Xg, const float* __restrict__ TXg,
             char* __restrict__ ws) {
    const _Float16* F16 = (const _Float16*)(ws + OFF_F16);
    const float* lg8    = (const float*)(ws + OFF_LG8);
    const float* invt   = (const float*)(ws + OFF_INV);
    const float* sqX    = (const float*)(ws + OFF_SQX);
    float* psum         = (float*)(ws + OFF_PSUM);
    double* chunk       = (double*)(ws + OFF_CHUNK);

    __shared__ float  s_dist[64];
    __shared__ double s_part[2][64];

    int bid = blockIdx.x;            // 2048 = m*32 + c
    int m = bid >> 5, c = bid & 31;
    int n0 = c << 6;
    int t = threadIdx.x;

    // ---- prologue: 64 distances for rows n0..n0+63 (2 threads per row) ----
    {
        int nloc = t >> 1, half = t & 1;
        const float4* T4 = (const float4*)(TXg + (size_t)(n0 + nloc) * D_ + (half << 7));
        const float4* X4 = (const float4*)(Xg + m * D_ + (half << 7));
        float4 dd{0,0,0,0}, ss{0,0,0,0};
#pragma unroll 8
        for (int k = 0; k < 32; ++k) {
            float4 tv = T4[k], xv = X4[k];
            dd.x = fmaf(xv.x, tv.x, dd.x); dd.y = fmaf(xv.y, tv.y, dd.y);
            dd.z = fmaf(xv.z, tv.z, dd.z); dd.w = fmaf(xv.w, tv.w, dd.w);
            ss.x = fmaf(tv.x, tv.x, ss.x); ss.y = fmaf(tv.y, tv.y, ss.y);
            ss.z = fmaf(tv.z, tv.z, ss.z); ss.w = fmaf(tv.w, tv.w, ss.w);
        }
        float dot = (dd.x + dd.y) + (dd.z + dd.w);
        float st  = (ss.x + ss.y) + (ss.z + ss.w);
        dot += __shfl_xor(dot, 1);
        st  += __shfl_xor(st, 1);
        if (half == 0)
            s_dist[nloc] = fmaxf(sqX[m] + st - 2.f * dot, 0.f);
    }
    __syncthreads();

    int w = t >> 6, l = t & 63;
    int col = l & 15, g = l >> 4;
    int rbase = n0 + (w << 5);       // wave rows rbase..rbase+31 (global n)

    float la0 = s_dist[(w << 5) + col]      * 0.125f;   // lambda = dist/8
    float la1 = s_dist[(w << 5) + 16 + col] * 0.125f;
    float ll0 = __logf(la0), ll1 = __logf(la1);

    f32x4 acc00 = {0,0,0,0}, acc01 = {0,0,0,0}, acc02 = {0,0,0,0}, acc03 = {0,0,0,0};
    f32x4 acc10 = {0,0,0,0}, acc11 = {0,0,0,0}, acc12 = {0,0,0,0}, acc13 = {0,0,0,0};

    for (int s = 0; s < 12; ++s) {
        int jb = (s << 5) + (g << 3);       // lane's k-base this step
        float jbf = (float)jb;
        half8 b0 = *(const half8*)(F16 + (size_t)(col     ) * J_ + jb);
        half8 b1 = *(const half8*)(F16 + (size_t)(col + 16) * J_ + jb);
        half8 b2 = *(const half8*)(F16 + (size_t)(col + 32) * J_ + jb);
        half8 b3 = *(const half8*)(F16 + (size_t)(col + 48) * J_ + jb);
        float lgv = lg8[(s << 2) + g];      // lgamma(jb+1)
        float4 iv0 = *(const float4*)(invt + jb);
        float4 iv1 = *(const float4*)(invt + jb + 4);
        {
            float wv = __expf(fmaf(jbf, ll0, -la0 - lgv));
            half8 a;
            a[0] = (_Float16)wv;
            wv *= la0 * iv0.x; a[1] = (_Float16)wv;
            wv *= la0 * iv0.y; a[2] = (_Float16)wv;
            wv *= la0 * iv0.z; a[3] = (_Float16)wv;
            wv *= la0 * iv0.w; a[4] = (_Float16)wv;
            wv *= la0 * iv1.x; a[5] = (_Float16)wv;
            wv *= la0 * iv1.y; a[6] = (_Float16)wv;
            wv *= la0 * iv1.z; a[7] = (_Float16)wv;
            acc00 = __builtin_amdgcn_mfma_f32_16x16x32_f16(a, b0, acc00, 0, 0, 0);
            acc01 = __builtin_amdgcn_mfma_f32_16x16x32_f16(a, b1, acc01, 0, 0, 0);
            acc02 = __builtin_amdgcn_mfma_f32_16x16x32_f16(a, b2, acc02, 0, 0, 0);
            acc03 = __builtin_amdgcn_mfma_f32_16x16x32_f16(a, b3, acc03, 0, 0, 0);
        }
        {
            float wv = __expf(fmaf(jbf, ll1, -la1 - lgv));
            half8 a;
            a[0] = (_Float16)wv;
            wv *= la1 * iv0.x; a[1] = (_Float16)wv;
            wv *= la1 * iv0.y; a[2] = (_Float16)wv;
            wv *= la1 * iv0.z; a[3] = (_Float16)wv;
            wv *= la1 * iv0.w; a[4] = (_Float16)wv;
            wv *= la1 * iv1.x; a[5] = (_Float16)wv;
            wv *= la1 * iv1.y; a[6] = (_Float16)wv;
            wv *= la1 * iv1.z; a[7] = (_Float16)wv;
            acc10 = __builtin_amdgcn_mfma_f32_16x16x32_f16(a, b0, acc10, 0, 0, 0);
            acc11 = __builtin_amdgcn_mfma_f32_16x16x32_f16(a, b1, acc11, 0, 0, 0);
            acc12 = __builtin_amdgcn_mfma_f32_16x16x32_f16(a, b2, acc12, 0, 0, 0);
            acc13 = __builtin_amdgcn_mfma_f32_16x16x32_f16(a, b3, acc13, 0, 0, 0);
        }
    }

    // ---- epilogue: psi = 1-R, store, per-chunk log-sums ----
    double lsum0 = 0.0, lsum1 = 0.0, lsum2 = 0.0, lsum3 = 0.0;
    float* pbase = psum + (((size_t)(m << 11) + rbase) << 6);
#define EPI(ACC, SP, TI, LS)                                                    \
    {                                                                           \
        _Pragma("unroll")                                                       \
        for (int r = 0; r < 4; ++r) {                                           \
            float ps = 1.f - (ACC)[r];                                          \
            int row = (SP) * 16 + g * 4 + r;                                    \
            pbase[((size_t)row << 6) + (TI) * 16 + col] = ps;                   \
            LS += (double)__logf(fmaxf(ps, 1e-30f));                            \
        }                                                                       \
    }
    EPI(acc00, 0, 0, lsum0) EPI(acc01, 0, 1, lsum1) EPI(acc02, 0, 2, lsum2) EPI(acc03, 0, 3, lsum3)
    EPI(acc10, 1, 0, lsum0) EPI(acc11, 1, 1, lsum1) EPI(acc12, 1, 2, lsum2) EPI(acc13, 1, 3, lsum3)
#undef EPI
    lsum0 += __shfl_xor(lsum0, 16); lsum0 += __shfl_xor(lsum0, 32);
    lsum1 += __shfl_xor(lsum1, 16); lsum1 += __shfl_xor(lsum1, 32);
    lsum2 += __shfl_xor(lsum2, 16); lsum2 += __shfl_xor(lsum2, 32);
    lsum3 += __shfl_xor(lsum3, 16); lsum3 += __shfl_xor(lsum3, 32);
    if (g == 0) {
        s_part[w][col]      = lsum0;
        s_part[w][16 + col] = lsum1;
        s_part[w][32 + col] = lsum2;
        s_part[w][48 + col] = lsum3;
    }
    __syncthreads();
    if (t < 64)
        chunk[((m << 5) + c) * 64 + t] = s_part[0][t] + s_part[1][t];
}

// merged prefix + scan: block (m,c) derives its own exclusive prefix + total
__global__ __launch_bounds__(64)
void k_scan(const int* __restrict__ ty, char* __restrict__ ws) {
    const float* psum   = (const float*)(ws + OFF_PSUM);
    const double* chunk = (const double*)(ws + OFF_CHUNK);
    float* pred         = (float*)(ws + OFF_PRED);
    int b = blockIdx.x, m = b >> 5, c = b & (CHUNKS - 1), l = threadIdx.x;

    double cum = 0.0, T = 0.0;
    for (int c2 = 0; c2 < CHUNKS; ++c2) {            // coalesced 512B loads
        double v = chunk[((m << 5) + c2) * 64 + l];
        T += v;
        if (c2 < c) cum += v;
    }

    const float* P = psum + (((size_t)m * N_ + (size_t)c * CN) << 6);
    int n0 = c * CN;
    float a0 = 0.f, a1 = 0.f;
    for (int i = 0; i < CN; ++i) {
        float pv = P[((size_t)i << 6) + l];
        float lv = __logf(fmaxf(pv, 1e-30f));
        double nbr = __shfl_down(cum, 1);           // cum[n-1, l+1]
        float pvn  = __shfl_down(pv, 1);            // psum[n, l+1]
        double cin = cum + (double)lv;              // cum[n, l]
        int n = n0 + i;
        double t1 = (n == 0) ? 0.0 : ((l == 63) ? -999999.0 : nbr);
        double t2 = T - cin;
        float e = (float)(t1 + t2);
        float pm = (l == 63) ? pv : (pv - pvn);
        float contrib = pm * __expf(e);
        int y = ty[n];                               // wave-uniform
        a0 += (y == 0) ? contrib : 0.f;
        a1 += (y == 1) ? contrib : 0.f;
        cum = cin;
    }
#pragma unroll
    for (int o = 32; o > 0; o >>= 1) {
        a0 += __shfl_down(a0, o);
        a1 += __shfl_down(a1, o);
    }
    if (l == 0) {
        atomicAdd(&pred[m * 2 + 0], a0);
        atomicAdd(&pred[m * 2 + 1], a1);
    }
}

__global__ __launch_bounds__(64)
void k_norm(char* __restrict__ ws, float* __restrict__ out) {
    const float* pred = (const float*)(ws + OFF_PRED);
    int m = threadIdx.x;
    float a = pred[2 * m], b = pred[2 * m + 1];
    float s = a + b;
    out[2 * m]     = a / s;
    out[2 * m + 1] = b / s;
}

extern "C" void kernel_launch(void* const* d_in, const int* in_sizes, int n_in,
                              void* d_out, int out_size, void* d_ws, size_t ws_size,
                              hipStream_t stream) {
    const float* X       = (const float*)d_in[0];
    const float* train_X = (const float*)d_in[1];
    const float* buckets = (const float*)d_in[2];
    const int*   train_y = (const int*)d_in[3];
    float* out = (float*)d_out;
    char*  ws  = (char*)d_ws;

    k_tab<<<13, 64, 0, stream>>>(buckets, X, ws);
    k_fused<<<M_ * CHUNKS, 128, 0, stream>>>(X, train_X, ws);
    k_scan<<<M_ * CHUNKS, 64, 0, stream>>>(train_y, ws);
    k_norm<<<1, 64, 0, stream>>>(ws, out);
}